// Round 7
// baseline (982.020 us; speedup 1.0000x reference)
//
#include <hip/hip_runtime.h>
#include <math.h>

// LRENet_2: L=4, AD=D=512, T=64, N=4096, NC=2, PROJ=256, HID=2048, CAP=16
#define LNUM 4
#define ADIM 512
#define TTOK 64
#define NSEQ 4096
#define HIDE 2048
#define CAPE 16
#define EPSV 1e-5f
#define LOG2E 1.44269504088896340736f

typedef __bf16 bf16;
typedef bf16 bf16x8 __attribute__((ext_vector_type(8)));
typedef float f32x4 __attribute__((ext_vector_type(4)));

#if __has_builtin(__builtin_amdgcn_exp2f)
#define EXP2F(x) __builtin_amdgcn_exp2f(x)
#else
#define EXP2F(x) __expf(0.69314718055994530942f * (x))
#endif

// ---------------- workspace layout (float offsets) ----------------
// zero region first (atomic-GEMM outputs + MoE buf + barrier counters)
#define OFF_BUF   0
#define OFF_SSUM  131072
#define OFF_CNT   131088
#define OFF_BAR   131104           // [0]=MEGA2 ctr, [1]=MEGA3 ctr
#define OFF_Q     131120
#define OFF_AP    (OFF_Q    + 131072)
#define OFF_QF    (OFF_AP   + 131072)
#define OFF_P     (OFF_QF   + 131072)
#define OFF_QKV3  (OFF_P    + 65536)
#define OFF_XB    (OFF_QKV3 + 98304)
#define OFF_HROW  (OFF_XB   + 32768)
#define OFF_GTD   (OFF_HROW + 131072)
#define OFF_HB    (OFF_GTD  + 32768)
#define ZERO_N    (OFF_HB   + 16384)     // = 901168 floats
#define NZB       ((ZERO_N + 255) / 256) // 3521 zero blocks
// non-zeroed
#define OFF_KT    ZERO_N
#define OFF_VT    (OFF_KT   + LNUM*512*NSEQ)
#define OFF_AO    (OFF_VT   + LNUM*512*NSEQ)  // shared: TN -> AO -> XN2 -> XN3
#define OFF_GATE  (OFF_AO   + 131072)
#define OFF_EXP   (OFF_GATE + 256)
#define OFF_POS   (OFF_EXP  + 256)
#define OFF_KEEP  (OFF_POS  + 256)
#define OFF_HEXP  (OFF_KEEP + 256)
#define OFF_CUR   (OFF_HEXP + LNUM*4*CAPE*HIDE)
#define OFF_AO2   (OFF_CUR  + TTOK*512)
#define OFF_AH    (OFF_AO2  + TTOK*512)   // bf16 (float slots = half count)
#define OFF_AL    (OFF_AH + LNUM*NSEQ*256)
#define OFF_WH    (OFF_AL + LNUM*NSEQ*256)
#define OFF_WL    (OFF_WH + LNUM*1024*256)
#define OFF_YEXP  OFF_AH                   // aliases AH (dead after k_l2)

// ---------------- output layout (floats) ----------------
#define O_F1   6
#define O_F2   (6 + LNUM*TTOK*512)
#define O_F2P  (O_F2 + LNUM*TTOK*512)

__device__ __forceinline__ float wave_sum(float v) {
#pragma unroll
  for (int o = 32; o > 0; o >>= 1) v += __shfl_down(v, o, 64);
  return v;
}
__device__ __forceinline__ float wave_sum_all(float v) {
#pragma unroll
  for (int o = 32; o > 0; o >>= 1) v += __shfl_xor(v, o, 64);
  return v;
}
__device__ __forceinline__ float block_sum256(float v) {
  __shared__ float r[4];
  v = wave_sum(v);
  int wid = threadIdx.x >> 6, lane = threadIdx.x & 63;
  if (lane == 0) r[wid] = v;
  __syncthreads();
  float s = r[0] + r[1] + r[2] + r[3];
  __syncthreads();
  return s;
}

// ---------------- software grid barrier (all blocks co-resident: grid <= 256) ----------------
__device__ __forceinline__ void gsync(unsigned* bar, unsigned target) {
  __syncthreads();
  if (threadIdx.x == 0) {
    __threadfence();
    atomicAdd(bar, 1u);
    while (__hip_atomic_load(bar, __ATOMIC_RELAXED, __HIP_MEMORY_SCOPE_AGENT) < target)
      __builtin_amdgcn_s_sleep(2);
  }
  __syncthreads();
  __threadfence();
}

// ---------------- LN of one 512-row by one wave (threads tid&63) ----------------
__device__ __forceinline__ void ln_row(const float* __restrict__ x,
      const float* __restrict__ G, const float* __restrict__ B, float* __restrict__ o) {
  int lane = threadIdx.x & 63;
  float4 a = *(const float4*)(x + lane * 8);
  float4 b = *(const float4*)(x + lane * 8 + 4);
  float sum = (a.x + a.y) + (a.z + a.w) + (b.x + b.y) + (b.z + b.w);
  float sq = a.x*a.x + a.y*a.y + a.z*a.z + a.w*a.w + b.x*b.x + b.y*b.y + b.z*b.z + b.w*b.w;
  sum = wave_sum_all(sum); sq = wave_sum_all(sq);
  float mu = sum * (1.f / 512.f);
  float rs = rsqrtf(sq * (1.f / 512.f) - mu * mu + EPSV);
  float4 g0 = *(const float4*)(G + lane * 8), g1 = *(const float4*)(G + lane * 8 + 4);
  float4 c0 = *(const float4*)(B + lane * 8), c1 = *(const float4*)(B + lane * 8 + 4);
  float4 o0, o1;
  o0.x = (a.x - mu) * rs * g0.x + c0.x;  o0.y = (a.y - mu) * rs * g0.y + c0.y;
  o0.z = (a.z - mu) * rs * g0.z + c0.z;  o0.w = (a.w - mu) * rs * g0.w + c0.w;
  o1.x = (b.x - mu) * rs * g1.x + c1.x;  o1.y = (b.y - mu) * rs * g1.y + c1.y;
  o1.z = (b.z - mu) * rs * g1.z + c1.z;  o1.w = (b.w - mu) * rs * g1.w + c1.w;
  *(float4*)(o + lane * 8) = o0; *(float4*)(o + lane * 8 + 4) = o1;
}

// ---------------- device GEMM tile: OUT[64 x N](n0..n0+64) (+)= IN[64 x K] @ W[N x K]^T ----------------
__device__ __forceinline__ void dev_gemm(
    const float* __restrict__ IN, const float* __restrict__ W,
    const float* __restrict__ BIAS, const float* __restrict__ RES,
    float* __restrict__ OUT, int K, int N, int n0, int kcBeg, int kcEnd,
    int doBias, int doAtomic, int act, float* sA, float* sB) {
  int tid = threadIdx.x;
  int tx = tid & 15, ty = tid >> 4;
  float acc[4][4];
  if (doBias) {
#pragma unroll
    for (int j = 0; j < 4; j++) {
      float bv = BIAS ? BIAS[n0 + tx*4 + j] : 0.f;
#pragma unroll
      for (int i = 0; i < 4; i++)
        acc[i][j] = bv + (RES ? RES[(size_t)(ty*4+i) * N + n0 + tx*4 + j] : 0.f);
    }
  } else {
#pragma unroll
    for (int i = 0; i < 4; i++)
#pragma unroll
      for (int j = 0; j < 4; j++) acc[i][j] = 0.f;
  }
  for (int kc = kcBeg; kc < kcEnd; kc += 64) {
    for (int i = tid; i < 1024; i += 256) {
      int r = i >> 4, kq = i & 15;
      float4 av = *(const float4*)(IN + (size_t)r * K + kc + kq*4);
      sA[(kq*4+0)*68 + r] = av.x; sA[(kq*4+1)*68 + r] = av.y;
      sA[(kq*4+2)*68 + r] = av.z; sA[(kq*4+3)*68 + r] = av.w;
      float4 bv = *(const float4*)(W + (size_t)(n0 + r) * K + kc + kq*4);
      sB[(kq*4+0)*68 + r] = bv.x; sB[(kq*4+1)*68 + r] = bv.y;
      sB[(kq*4+2)*68 + r] = bv.z; sB[(kq*4+3)*68 + r] = bv.w;
    }
    __syncthreads();
#pragma unroll 8
    for (int kk = 0; kk < 64; kk++) {
      float4 a4 = *(const float4*)&sA[kk*68 + ty*4];
      float4 b4 = *(const float4*)&sB[kk*68 + tx*4];
      float a[4] = {a4.x,a4.y,a4.z,a4.w}, b[4] = {b4.x,b4.y,b4.z,b4.w};
#pragma unroll
      for (int i = 0; i < 4; i++)
#pragma unroll
        for (int j = 0; j < 4; j++) acc[i][j] = fmaf(a[i], b[j], acc[i][j]);
    }
    __syncthreads();
  }
  if (doAtomic) {
#pragma unroll
    for (int i = 0; i < 4; i++)
#pragma unroll
      for (int j = 0; j < 4; j++)
        atomicAdd(&OUT[(size_t)(ty*4+i) * N + n0 + tx*4 + j], acc[i][j]);
  } else {
#pragma unroll
    for (int i = 0; i < 4; i++)
#pragma unroll
      for (int j = 0; j < 4; j++) {
        float o = acc[i][j];
        if (act == 1) o = o / (1.f + __expf(-1.702f * o));
        OUT[(size_t)(ty*4+i) * N + n0 + tx*4 + j] = o;
      }
  }
}

// transposed-W variant: W stored [K][N]
__device__ __forceinline__ void dev_gemmt(
    const float* __restrict__ IN, const float* __restrict__ W,
    float* __restrict__ OUT, int K, int N, int n0, int kcBeg, int kcEnd,
    float* sA, float* sB) {
  int tid = threadIdx.x;
  int tx = tid & 15, ty = tid >> 4;
  float acc[4][4] = {};
  for (int kc = kcBeg; kc < kcEnd; kc += 64) {
    for (int i = tid; i < 1024; i += 256) {
      int r = i >> 4, kq = i & 15;
      float4 av = *(const float4*)(IN + (size_t)r * K + kc + kq*4);
      sA[(kq*4+0)*68 + r] = av.x; sA[(kq*4+1)*68 + r] = av.y;
      sA[(kq*4+2)*68 + r] = av.z; sA[(kq*4+3)*68 + r] = av.w;
      float4 bv = *(const float4*)(W + (size_t)(kc + r) * N + n0 + kq*4);
      *(float4*)&sB[r*68 + kq*4] = bv;
    }
    __syncthreads();
#pragma unroll 8
    for (int kk = 0; kk < 64; kk++) {
      float4 a4 = *(const float4*)&sA[kk*68 + ty*4];
      float4 b4 = *(const float4*)&sB[kk*68 + tx*4];
      float a[4] = {a4.x,a4.y,a4.z,a4.w}, b[4] = {b4.x,b4.y,b4.z,b4.w};
#pragma unroll
      for (int i = 0; i < 4; i++)
#pragma unroll
        for (int j = 0; j < 4; j++) acc[i][j] = fmaf(a[i], b[j], acc[i][j]);
    }
    __syncthreads();
  }
#pragma unroll
  for (int i = 0; i < 4; i++)
#pragma unroll
    for (int j = 0; j < 4; j++)
      atomicAdd(&OUT[(size_t)(ty*4+i) * N + n0 + tx*4 + j], acc[i][j]);
}

// ================= MEGA1: zero + cvt_a + cvt_w + tok-LN =================
__global__ __launch_bounds__(256) void k_mega1(
    const float* __restrict__ SF, const float* __restrict__ LN1G, const float* __restrict__ LN1B,
    const float* __restrict__ Wqkv, const float* __restrict__ TOK,
    const float* __restrict__ LN2G, const float* __restrict__ LN2B,
    bf16* __restrict__ AH, bf16* __restrict__ AL,
    bf16* __restrict__ WH, bf16* __restrict__ WL,
    float* __restrict__ XN, float* __restrict__ ws) {
  int bid = blockIdx.x, tid = threadIdx.x;
  if (bid < NZB) {
    int i = bid * 256 + tid;
    if (i < ZERO_N) ws[i] = 0.f;
    return;
  }
  bid -= NZB;
  int wave = tid >> 6, lane = tid & 63;
  if (bid < 4096) {                    // cvt_a: LN + split-bf16, 4 rows/block
    int row = bid * 4 + wave;          // l*4096 + m
    int l = row >> 12, m = row & 4095;
    const float* src = SF + (size_t)m * (LNUM * ADIM) + l * ADIM;
    float4 a = *(const float4*)(src + lane * 8);
    float4 b = *(const float4*)(src + lane * 8 + 4);
    float sum = (a.x + a.y) + (a.z + a.w) + (b.x + b.y) + (b.z + b.w);
    float sq = a.x*a.x + a.y*a.y + a.z*a.z + a.w*a.w + b.x*b.x + b.y*b.y + b.z*b.z + b.w*b.w;
    sum = wave_sum_all(sum); sq = wave_sum_all(sq);
    float mu = sum * (1.f / 512.f);
    float rs = rsqrtf(sq * (1.f / 512.f) - mu * mu + EPSV);
    float4 g0 = *(const float4*)(LN1G + l * 512 + lane * 8);
    float4 g1 = *(const float4*)(LN1G + l * 512 + lane * 8 + 4);
    float4 c0 = *(const float4*)(LN1B + l * 512 + lane * 8);
    float4 c1 = *(const float4*)(LN1B + l * 512 + lane * 8 + 4);
    float x[8];
    x[0] = (a.x - mu) * rs * g0.x + c0.x;  x[1] = (a.y - mu) * rs * g0.y + c0.y;
    x[2] = (a.z - mu) * rs * g0.z + c0.z;  x[3] = (a.w - mu) * rs * g0.w + c0.w;
    x[4] = (b.x - mu) * rs * g1.x + c1.x;  x[5] = (b.y - mu) * rs * g1.y + c1.y;
    x[6] = (b.z - mu) * rs * g1.z + c1.z;  x[7] = (b.w - mu) * rs * g1.w + c1.w;
    bf16x8 vh, vl;
#pragma unroll
    for (int j = 0; j < 8; j++) {
      bf16 h = (bf16)x[j];
      vh[j] = h;
      vl[j] = (bf16)(x[j] - (float)h);
    }
    *(bf16x8*)(AH + (size_t)row * 512 + lane * 8) = vh;
    *(bf16x8*)(AL + (size_t)row * 512 + lane * 8) = vl;
    return;
  }
  bid -= 4096;
  if (bid < 1024) {                    // cvt_w: 4 rows/block
    int row = bid * 4 + wave;          // l*1024 + r
    int l = row >> 10, r = row & 1023;
    const float* src = Wqkv + (size_t)l * 1536 * 512 + (size_t)(512 + r) * 512 + lane * 8;
    float4 a = *(const float4*)(src);
    float4 b = *(const float4*)(src + 4);
    float x[8] = {a.x, a.y, a.z, a.w, b.x, b.y, b.z, b.w};
    bf16x8 vh, vl;
#pragma unroll
    for (int j = 0; j < 8; j++) {
      bf16 h = (bf16)x[j];
      vh[j] = h;
      vl[j] = (bf16)(x[j] - (float)h);
    }
    *(bf16x8*)(WH + (size_t)row * 512 + lane * 8) = vh;
    *(bf16x8*)(WL + (size_t)row * 512 + lane * 8) = vl;
    return;
  }
  bid -= 1024;
  {                                    // tok LN: 4 rows/block, 64 blocks (256 rows)
    int row = bid * 4 + wave;          // l*64 + t
    int l = row >> 6;
    ln_row(TOK + (size_t)row * 512, LN2G + l * 512, LN2B + l * 512, XN + (size_t)row * 512);
  }
}

// ================= L2: split-bf16 MFMA K/V GEMM + Q-proj GEMM =================
#define KVP 40
__global__ __launch_bounds__(256) void k_l2(
    const bf16* __restrict__ AH, const bf16* __restrict__ AL,
    const bf16* __restrict__ WH, const bf16* __restrict__ WL,
    const float* __restrict__ Bqkv, const float* __restrict__ Wqkv,
    const float* __restrict__ XN,
    float* __restrict__ KT, float* __restrict__ VT, float* __restrict__ Q) {
  __shared__ char smem[4 * 128 * KVP * sizeof(bf16)];   // 40960 B
  int bid = blockIdx.x;
  int tid = threadIdx.x;
  if (bid < 1024) {
    bf16* sAh = (bf16*)smem;
    bf16* sAl = sAh + 128 * KVP;
    bf16* sWh = sAl + 128 * KVP;
    bf16* sWl = sWh + 128 * KVP;
    int l = bid >> 8, rem = bid & 255;
    int n0 = (rem >> 5) * 128, m0 = (rem & 31) * 128;   // m fastest -> same-XCD A reuse
    int lane = tid & 63;
    int w = tid >> 6;
    int wm = w >> 1, wn = w & 1;
    const bf16* gAh = AH + ((size_t)l * 4096 + m0) * 512;
    const bf16* gAl = AL + ((size_t)l * 4096 + m0) * 512;
    const bf16* gWh = WH + ((size_t)l * 1024 + n0) * 512;
    const bf16* gWl = WL + ((size_t)l * 1024 + n0) * 512;
    int ch0 = tid * 2, ch1 = tid * 2 + 1;
    int r0 = ch0 >> 2, q0 = (ch0 & 3) * 8;
    int r1 = ch1 >> 2, q1 = (ch1 & 3) * 8;
    int fr = lane & 15, fq = (lane >> 4) * 8;
    f32x4 acc[4][4] = {};
    for (int k0 = 0; k0 < 512; k0 += 32) {
      *(bf16x8*)&sAh[r0*KVP + q0] = *(const bf16x8*)&gAh[(size_t)r0*512 + k0 + q0];
      *(bf16x8*)&sAh[r1*KVP + q1] = *(const bf16x8*)&gAh[(size_t)r1*512 + k0 + q1];
      *(bf16x8*)&sAl[r0*KVP + q0] = *(const bf16x8*)&gAl[(size_t)r0*512 + k0 + q0];
      *(bf16x8*)&sAl[r1*KVP + q1] = *(const bf16x8*)&gAl[(size_t)r1*512 + k0 + q1];
      *(bf16x8*)&sWh[r0*KVP + q0] = *(const bf16x8*)&gWh[(size_t)r0*512 + k0 + q0];
      *(bf16x8*)&sWh[r1*KVP + q1] = *(const bf16x8*)&gWh[(size_t)r1*512 + k0 + q1];
      *(bf16x8*)&sWl[r0*KVP + q0] = *(const bf16x8*)&gWl[(size_t)r0*512 + k0 + q0];
      *(bf16x8*)&sWl[r1*KVP + q1] = *(const bf16x8*)&gWl[(size_t)r1*512 + k0 + q1];
      __syncthreads();
      bf16x8 ah[4], al[4], bh[4], bl[4];
#pragma unroll
      for (int i = 0; i < 4; i++) {
        ah[i] = *(const bf16x8*)&sAh[(wm*64 + i*16 + fr)*KVP + fq];
        al[i] = *(const bf16x8*)&sAl[(wm*64 + i*16 + fr)*KVP + fq];
        bh[i] = *(const bf16x8*)&sWh[(wn*64 + i*16 + fr)*KVP + fq];
        bl[i] = *(const bf16x8*)&sWl[(wn*64 + i*16 + fr)*KVP + fq];
      }
#pragma unroll
      for (int i = 0; i < 4; i++)
#pragma unroll
        for (int j = 0; j < 4; j++) {
          acc[i][j] = __builtin_amdgcn_mfma_f32_16x16x32_bf16(ah[i], bh[j], acc[i][j], 0, 0, 0);
          acc[i][j] = __builtin_amdgcn_mfma_f32_16x16x32_bf16(ah[i], bl[j], acc[i][j], 0, 0, 0);
          acc[i][j] = __builtin_amdgcn_mfma_f32_16x16x32_bf16(al[i], bh[j], acc[i][j], 0, 0, 0);
        }
      __syncthreads();
    }
#pragma unroll
    for (int j = 0; j < 4; j++) {
      int n = n0 + wn*64 + j*16 + fr;
      float bias = Bqkv[l * 1536 + 512 + n];
      float* base = (n < 512) ? (KT + ((size_t)(l*512 + n)) * 4096)
                              : (VT + ((size_t)(l*512 + n - 512)) * 4096);
#pragma unroll
      for (int i = 0; i < 4; i++) {
        int mb = m0 + wm*64 + i*16 + (lane >> 4) * 4;
        float4 o = make_float4(acc[i][j][0] + bias, acc[i][j][1] + bias,
                               acc[i][j][2] + bias, acc[i][j][3] + bias);
        *(float4*)(base + mb) = o;
      }
    }
  } else {
    // Q-proj: 128 blocks, split-K 4 x 128, atomic into pre-zeroed Q
    float* sA = (float*)smem;
    float* sB = sA + 64 * 68;
    int rem = bid - 1024;
    int l = rem >> 5, r2 = rem & 31, kcb = r2 >> 3, nb = r2 & 7;
    dev_gemm(XN + (size_t)l * 64 * 512, Wqkv + (size_t)l * 1536 * 512,
             Bqkv + l * 1536, nullptr, Q + (size_t)l * 64 * 512,
             512, 512, nb * 64, kcb * 128, kcb * 128 + 128, kcb == 0, 1, 0, sA, sB);
  }
}

// ================= hd=1 attention (register K/V, fused min/max, native exp2) =================
__global__ __launch_bounds__(256) void k_attn(const float* __restrict__ KT, const float* __restrict__ VT,
      const float* __restrict__ Q, float* __restrict__ AO) {
  int h = blockIdx.x, l = blockIdx.y;
  int tid = threadIdx.x;
  int w = tid >> 6, lane = tid & 63;
  __shared__ float2 sacc[4][8][66];
  __shared__ float wmx[4], wmn[4];
  size_t base = ((size_t)(l * 512 + h)) * 4096 + w * 1024;
  float kv[16], vv[16];
#pragma unroll
  for (int c = 0; c < 4; c++) {
    *(float4*)&kv[c*4] = *(const float4*)(KT + base + c * 256 + lane * 4);
    *(float4*)&vv[c*4] = *(const float4*)(VT + base + c * 256 + lane * 4);
  }
  float mx = kv[0], mn = kv[0];
#pragma unroll
  for (int i = 1; i < 16; i++) { mx = fmaxf(mx, kv[i]); mn = fminf(mn, kv[i]); }
#pragma unroll
  for (int o = 32; o > 0; o >>= 1) {
    mx = fmaxf(mx, __shfl_xor(mx, o, 64));
    mn = fminf(mn, __shfl_xor(mn, o, 64));
  }
  if (lane == 0) { wmx[w] = mx; wmn[w] = mn; }
  __syncthreads();
  float km = fmaxf(fmaxf(wmx[0], wmx[1]), fmaxf(wmx[2], wmx[3]));
  float kn = fminf(fminf(wmn[0], wmn[1]), fminf(wmn[2], wmn[3]));
  float q_own = Q[((size_t)l * TTOK + lane) * 512 + h];
  float q2_own = q_own * LOG2E;
  float m2_own = ((q_own >= 0.f) ? q_own * km : q_own * kn) * LOG2E;  // exact max (hd=1)
  int rt = tid >> 5, rj = tid & 31;
  for (int cc = 0; cc < 8; cc++) {
    for (int tt = 0; tt < 8; tt++) {
      int t = cc * 8 + tt;
      float q2t = __shfl(q2_own, t, 64);
      float m2t = __shfl(m2_own, t, 64);
      float den = 0.f, num = 0.f;
#pragma unroll
      for (int i = 0; i < 16; i++) {
        float e = EXP2F(fmaf(q2t, kv[i], -m2t));
        den += e;
        num = fmaf(e, vv[i], num);
      }
      sacc[w][tt][lane] = make_float2(den, num);
    }
    __syncthreads();
    float2 a = make_float2(0.f, 0.f);
#pragma unroll
    for (int g = 0; g < 4; g++)
#pragma unroll
      for (int s2 = 0; s2 < 2; s2++) {
        float2 v = sacc[g][rt][rj + 32 * s2];
        a.x += v.x; a.y += v.y;
      }
#pragma unroll
    for (int o = 16; o > 0; o >>= 1) {
      a.x += __shfl_down(a.x, o, 32);
      a.y += __shfl_down(a.y, o, 32);
    }
    if (rj == 0) {
      int t = cc * 8 + rt;
      AO[((size_t)l * TTOK + t) * 512 + h] = a.y / a.x;
    }
    __syncthreads();
  }
}

// ================= MEGA2: out-proj -> mlp -> gate -> route/scatter -> experts -> combine =================
__global__ __launch_bounds__(256) void k_mega2(
    const float* __restrict__ AO, const float* __restrict__ OUTW, const float* __restrict__ OUTB,
    float* __restrict__ AP, const float* __restrict__ MLPW, const float* __restrict__ MLPB,
    float* __restrict__ QF, const float* __restrict__ GPW, float* __restrict__ P,
    const float* __restrict__ SIM, const float* __restrict__ TEMP,
    float* __restrict__ GATE, int* __restrict__ EXPI, int* __restrict__ POSI, int* __restrict__ KEEPI,
    float* __restrict__ SSUM, int* __restrict__ CNT, float* __restrict__ BUF,
    const float* __restrict__ EW1, const float* __restrict__ EB1, float* __restrict__ HEXP,
    const float* __restrict__ EW2, const float* __restrict__ EB2, float* __restrict__ YEXP,
    float* __restrict__ f1, float* __restrict__ f2, float* __restrict__ CUR,
    unsigned* __restrict__ bar) {
  __shared__ float smem[8704];
  float* sA = smem;
  float* sB = smem + 64 * 68;
  int bid = blockIdx.x;    // 128 blocks
  int tid = threadIdx.x;
  { // s1: out-proj AO @ OUTW -> AP (split-K 4)
    int l = bid >> 5, r = bid & 31, kcb = r >> 3, nb = r & 7;
    dev_gemm(AO + (size_t)l*64*512, OUTW + (size_t)l*512*512, OUTB + l*512, nullptr,
             AP + (size_t)l*64*512, 512, 512, nb*64, kcb*128, kcb*128+128, kcb == 0, 1, 0, sA, sB);
  }
  gsync(bar, 128);
  { // s2: mlp AP @ MLPW -> QF
    int l = bid >> 5, r = bid & 31, kcb = r >> 3, nb = r & 7;
    dev_gemm(AP + (size_t)l*64*512, MLPW + (size_t)l*512*512, MLPB + l*512, nullptr,
             QF + (size_t)l*64*512, 512, 512, nb*64, kcb*128, kcb*128+128, kcb == 0, 1, 0, sA, sB);
  }
  gsync(bar, 256);
  if (bid < 64) { // s3: gate proj QF @ GPW -> P
    int l = bid >> 4, r = bid & 15, kcb = r >> 2, nb = r & 3;
    dev_gemmt(QF + (size_t)l*64*512, GPW, P + (size_t)l*64*256, 512, 256,
              nb*64, kcb*128, kcb*128+128, sA, sB);
  }
  gsync(bar, 384);
  if (bid < 4) { // s4: gate + route + scatter, l = bid
    int l = bid;
    int t = tid >> 2, q = tid & 3;
    float* score_s = smem;               // [4][64]
    float* g_s = smem + 256;             // [64]
    int* e_s = (int*)(smem + 320);
    int* keep_s = e_s + 64;
    int* pos_s = keep_s + 64;
    const float* prow = P + ((size_t)(l * 64 + t)) * 256 + q * 64;
    float ss = 0.f, le[4] = {}, ne[4] = {};
    for (int j = 0; j < 64; j++) {
      float pv = prow[j];
      ss = fmaf(pv, pv, ss);
      float4 s4 = *(const float4*)(SIM + (size_t)(q * 64 + j) * 4);
      le[0] = fmaf(pv, s4.x, le[0]); le[1] = fmaf(pv, s4.y, le[1]);
      le[2] = fmaf(pv, s4.z, le[2]); le[3] = fmaf(pv, s4.w, le[3]);
      ne[0] = fmaf(s4.x, s4.x, ne[0]); ne[1] = fmaf(s4.y, s4.y, ne[1]);
      ne[2] = fmaf(s4.z, s4.z, ne[2]); ne[3] = fmaf(s4.w, s4.w, ne[3]);
    }
#pragma unroll
    for (int o = 2; o > 0; o >>= 1) {
      ss += __shfl_xor(ss, o, 4);
#pragma unroll
      for (int e = 0; e < 4; e++) { le[e] += __shfl_xor(le[e], o, 4); ne[e] += __shfl_xor(ne[e], o, 4); }
    }
    if (q == 0) {
      float invp = 1.f / (sqrtf(ss) + 1e-8f);
      float scale = __expf(fminf(TEMP[0], 4.6051701859880914f));  // min(temp, log 100)
      float lg[4];
#pragma unroll
      for (int e = 0; e < 4; e++) lg[e] = le[e] * invp / (sqrtf(ne[e]) + 1e-8f) * scale;
      int best = 0; float bv = lg[0];
      if (lg[1] > bv) { best = 1; bv = lg[1]; }
      if (lg[2] > bv) { best = 2; bv = lg[2]; }
      if (lg[3] > bv) { best = 3; bv = lg[3]; }
      float mxl = fmaxf(fmaxf(lg[0], lg[1]), fmaxf(lg[2], lg[3]));
      float e0 = __expf(lg[0]-mxl), e1 = __expf(lg[1]-mxl), e2 = __expf(lg[2]-mxl), e3 = __expf(lg[3]-mxl);
      float inv = 1.f / (e0 + e1 + e2 + e3);
      score_s[0*64+t] = e0*inv; score_s[1*64+t] = e1*inv;
      score_s[2*64+t] = e2*inv; score_s[3*64+t] = e3*inv;
      float sb = score_s[best*64+t];
      g_s[t] = sb; e_s[t] = best;
      GATE[l * TTOK + t] = sb;
      EXPI[l * TTOK + t] = best;
    }
    __syncthreads();
    if (tid < 64) {
      float gt = g_s[tid]; int et = e_s[tid];
      int p = 0;
      for (int u = 0; u < 64; u++)
        if (e_s[u] == et && (g_s[u] > gt || (g_s[u] == gt && u < tid))) p++;
      pos_s[tid] = p; keep_s[tid] = (p < CAPE) ? 1 : 0;
      POSI[l * TTOK + tid] = p;
      KEEPI[l * TTOK + tid] = (p < CAPE) ? 1 : 0;
    } else if (tid < 68) {
      int e = tid - 64;
      float s = 0.f; int c = 0;
      for (int u = 0; u < 64; u++) { s += score_s[e*64+u]; c += (e_s[u] == e); }
      SSUM[l * 4 + e] = s;
      CNT[l * 4 + e] = c;
    }
    __syncthreads();
    int which = tid >> 7, idx = tid & 127;
    for (int tb = 0; tb < 64; tb += 2) {
      int tt = tb + which;
      if (keep_s[tt]) {
        float4* dst = (float4*)(BUF + (((size_t)(l * 4 + e_s[tt])) * CAPE + pos_s[tt]) * 512);
        dst[idx] = ((const float4*)(QF + ((size_t)l * TTOK + tt) * 512))[idx];
      }
    }
  }
  gsync(bar, 512);
  { // s5: expert up-proj + gelu
    int le = bid >> 3;
    int e = le & 3;
    int col = (bid & 7) * 256 + tid;
    const float* act = BUF + (size_t)le * 16 * 512;
    const float* wp = EW1 + (size_t)e * 512 * HIDE + col;
    float acc[16];
#pragma unroll
    for (int c = 0; c < 16; c++) acc[c] = 0.f;
    for (int k0 = 0; k0 < 512; k0 += 4) {
      float4 a[16];
#pragma unroll
      for (int c = 0; c < 16; c++) a[c] = *(const float4*)(act + c * 512 + k0);
#pragma unroll
      for (int j = 0; j < 4; j++) {
        float wv = wp[(size_t)(k0 + j) * HIDE];
#pragma unroll
        for (int c = 0; c < 16; c++) acc[c] = fmaf(((const float*)&a[c])[j], wv, acc[c]);
      }
    }
    float bias = EB1[e * HIDE + col];
    float* outp = HEXP + (size_t)le * 16 * HIDE + col;
#pragma unroll
    for (int c = 0; c < 16; c++) {
      float v = acc[c] + bias;
      outp[(size_t)c * HIDE] = 0.5f * v * (1.f + erff(v * 0.70710678118654752f));
    }
  }
  gsync(bar, 640);
  { // s6: expert down-proj (k split over 4 waves, LDS reduce)
    int le = bid >> 3;
    int e = le & 3;
    int cl = tid & 63, kq = tid >> 6;
    int col = (bid & 7) * 64 + cl;
    const float* act = HEXP + (size_t)le * 16 * HIDE + kq * 512;
    const float* wp = EW2 + (size_t)e * HIDE * 512 + (size_t)(kq * 512) * 512 + col;
    float acc[16];
#pragma unroll
    for (int c = 0; c < 16; c++) acc[c] = 0.f;
    for (int k0 = 0; k0 < 512; k0 += 4) {
      float4 a[16];
#pragma unroll
      for (int c = 0; c < 16; c++) a[c] = *(const float4*)(act + c * HIDE + k0);
#pragma unroll
      for (int j = 0; j < 4; j++) {
        float wv = wp[(size_t)(k0 + j) * 512];
#pragma unroll
        for (int c = 0; c < 16; c++) acc[c] = fmaf(((const float*)&a[c])[j], wv, acc[c]);
      }
    }
    float* sacc = smem;   // [4][16][64]
    __syncthreads();
#pragma unroll
    for (int c = 0; c < 16; c++) sacc[(kq*16 + c)*64 + cl] = acc[c];
    __syncthreads();
    if (kq == 0) {
      float bias = EB2[e * 512 + col];
#pragma unroll
      for (int c = 0; c < 16; c++) {
        float tot = sacc[(0*16+c)*64+cl] + sacc[(1*16+c)*64+cl]
                  + sacc[(2*16+c)*64+cl] + sacc[(3*16+c)*64+cl] + bias;
        YEXP[(size_t)le * 16 * 512 + (size_t)c * 512 + col] = tot;
      }
    }
  }
  gsync(bar, 768);
  if (bid < 64) { // s7: combine -> f1, f2, CUR (t = bid, 256 threads x 2 cols)
    int t = bid;
    int d0 = tid, d1 = tid + 256;
    float a0 = 0.f, a1 = 0.f;
#pragma unroll
    for (int l = 0; l < LNUM; l++) {
      int idx = l * TTOK + t;
      if (KEEPI[idx]) {
        size_t b = (((size_t)(l * 4 + EXPI[idx])) * CAPE + POSI[idx]) * 512;
        float g = GATE[idx];
        a0 = fmaf(YEXP[b + d0], g, a0);
        a1 = fmaf(YEXP[b + d1], g, a1);
      }
      size_t r = ((size_t)l * TTOK + t) * 512;
      f1[r + d0] = a0; f1[r + d1] = a1;
      f2[r + d0] = 0.f; f2[r + d1] = 0.f;
    }
    CUR[(size_t)t * 512 + d0] = a0 * 0.25f;
    CUR[(size_t)t * 512 + d1] = a1 * 0.25f;
  }
}

// ================= MEGA3: GSA block + classifier =================
__global__ __launch_bounds__(256) void k_mega3(
    const float* __restrict__ CUR, const float* __restrict__ GL1G, const float* __restrict__ GL1B,
    float* __restrict__ XN, const float* __restrict__ GQKVW, const float* __restrict__ GQKVB,
    float* __restrict__ QKV3, float* __restrict__ AO2,
    const float* __restrict__ GOUTW, const float* __restrict__ GOUTB, float* __restrict__ XB,
    const float* __restrict__ GL2G, const float* __restrict__ GL2B,
    const float* __restrict__ GFCW, const float* __restrict__ GFCB, float* __restrict__ HROW,
    const float* __restrict__ GPJW, const float* __restrict__ GPJB, float* __restrict__ GTD,
    const float* __restrict__ BTW, const float* __restrict__ BTB, float* __restrict__ HBB,
    const float* __restrict__ CLW, const float* __restrict__ CLB,
    const float* __restrict__ SSUM, const int* __restrict__ CNT,
    float* __restrict__ out, unsigned* __restrict__ bar) {
  __shared__ float smem[12736];
  float* sA = smem;
  float* sB = smem + 64 * 68;
  int bid = blockIdx.x;    // 64 blocks
  int tid = threadIdx.x;
  // s0: LN(CUR) -> XN  (one row per block, wave 0)
  if (tid < 64) ln_row(CUR + (size_t)bid * 512, GL1G, GL1B, XN + (size_t)bid * 512);
  gsync(bar, 64);
  // s1: qkv GEMM XN @ GQKVW -> QKV3 (N=1536, split-K 2)
  if (bid < 48) {
    int nb = bid % 24, kcb = bid / 24;
    dev_gemm(XN, GQKVW, GQKVB, nullptr, QKV3, 512, 1536, nb*64,
             kcb*256, kcb*256+256, kcb == 0, 1, 0, sA, sB);
  }
  gsync(bar, 128);
  // s2: GSA attention, h = bid < 8
  if (bid < 8) {
    int h = bid;
    float* qh = smem;                 // [64][65]
    float* kh = smem + 4160;
    float* vh = smem + 8320;
    float* ps = smem + 12480;         // [4][64]
    __syncthreads();
    for (int i = tid; i < 4096; i += 256) {
      int t = i >> 6, d = i & 63;
      qh[t*65 + d] = QKV3[(size_t)t * 1536 + h * 64 + d];
      kh[t*65 + d] = QKV3[(size_t)t * 1536 + 512 + h * 64 + d];
      vh[t*65 + d] = QKV3[(size_t)t * 1536 + 1024 + h * 64 + d];
    }
    __syncthreads();
    int w = tid >> 6, lane = tid & 63;
    for (int tt = 0; tt < 16; tt++) {
      int t = w * 16 + tt;
      float acc = 0.f;
#pragma unroll 8
      for (int d = 0; d < 64; d++) acc = fmaf(qh[t*65 + d], kh[lane*65 + d], acc);
      acc *= 0.125f;
      float m = acc;
#pragma unroll
      for (int o = 32; o > 0; o >>= 1) m = fmaxf(m, __shfl_xor(m, o, 64));
      float e = __expf(acc - m);
      float den = e;
#pragma unroll
      for (int o = 32; o > 0; o >>= 1) den += __shfl_xor(den, o, 64);
      ps[w*64 + lane] = e / den;
      __syncthreads();
      float o2 = 0.f;
#pragma unroll 8
      for (int s = 0; s < 64; s++) o2 = fmaf(ps[w*64 + s], vh[s*65 + lane], o2);
      AO2[(size_t)t * 512 + h * 64 + lane] = o2;
      __syncthreads();
    }
  }
  gsync(bar, 192);
  // s3: out-proj + residual CUR -> XB (split-K 2)
  if (bid < 16) {
    int nb = bid & 7, kcb = bid >> 3;
    dev_gemm(AO2, GOUTW, GOUTB, CUR, XB, 512, 512, nb*64,
             kcb*256, kcb*256+256, kcb == 0, 1, 0, sA, sB);
  }
  gsync(bar, 256);
  // s4: LN(XB) -> XN
  if (tid < 64) ln_row(XB + (size_t)bid * 512, GL2G, GL2B, XN + (size_t)bid * 512);
  gsync(bar, 320);
  // s5: fc + swish (whole-K, direct store)
  if (bid < 32)
    dev_gemm(XN, GFCW, GFCB, nullptr, HROW, 512, 2048, bid*64, 0, 512, 1, 0, 1, sA, sB);
  gsync(bar, 384);
  // s6: proj + residual XB -> GTD (K=2048, split-K 4)
  if (bid < 32) {
    int nb = bid & 7, kcb = bid >> 3;
    dev_gemm(HROW, GPJW, GPJB, XB, GTD, 2048, 512, nb*64,
             kcb*512, kcb*512+512, kcb == 0, 1, 0, sA, sB);
  }
  gsync(bar, 448);
  // s7: butter -> HBB (N=256, split-K 2)
  if (bid < 8) {
    int nb = bid & 3, kcb = bid >> 2;
    dev_gemm(GTD, BTW, BTB, nullptr, HBB, 512, 256, nb*64,
             kcb*256, kcb*256+256, kcb == 0, 1, 0, sA, sB);
  }
  gsync(bar, 512);
  // s8: classifier head + aux + feature2_pre
  if (bid == 0) {
    float p0 = 0.f, p1 = 0.f;
    for (int i = tid; i < 16384; i += 256) {
      float h = HBB[i];
      p0 = fmaf(h, CLW[i], p0);
      p1 = fmaf(h, CLW[16384 + i], p1);
    }
    p0 = block_sum256(p0);
    p1 = block_sum256(p1);
    if (tid == 0) {
      float l0 = p0 + CLB[0], l1 = p1 + CLB[1];
      out[0] = l0; out[1] = l1;
      out[2] = 1.f / (1.f + __expf(-l0));
      out[3] = 1.f / (1.f + __expf(-l1));
      out[4] = (l1 > l0) ? 1.f : 0.f;   // argmax, first max on ties
      float aux = 0.f;
      for (int i = 0; i < 16; i++) aux += (SSUM[i] * (1.f / 64.f)) * ((float)CNT[i] * (1.f / 64.f));
      out[5] = aux * 4.f * 0.01f;
    }
  }
  if (bid == 1 && tid < 8) out[O_F2P + tid] = 0.f;
}

extern "C" void kernel_launch(void* const* d_in, const int* in_sizes, int n_in,
                              void* d_out, int out_size, void* d_ws, size_t ws_size,
                              hipStream_t stream) {
  const float* SF    = (const float*)d_in[0];
  const float* TOK   = (const float*)d_in[1];
  const float* LN1G  = (const float*)d_in[2];
  const float* LN1B  = (const float*)d_in[3];
  const float* LN2G  = (const float*)d_in[4];
  const float* LN2B  = (const float*)d_in[5];
  const float* QKVW  = (const float*)d_in[6];
  const float* QKVB  = (const float*)d_in[7];
  const float* OUTW  = (const float*)d_in[8];
  const float* OUTB  = (const float*)d_in[9];
  const float* MLPW  = (const float*)d_in[10];
  const float* MLPB  = (const float*)d_in[11];
  const float* GPW   = (const float*)d_in[12];
  const float* GSIM  = (const float*)d_in[13];
  const float* GTMP  = (const float*)d_in[14];
  const float* EW1   = (const float*)d_in[15];
  const float* EB1   = (const float*)d_in[16];
  const float* EW2   = (const float*)d_in[17];
  const float* EB2   = (const float*)d_in[18];
  const float* GL1G  = (const float*)d_in[19];
  const float* GL1B  = (const float*)d_in[20];
  const float* GQKVW = (const float*)d_in[21];
  const float* GQKVB = (const float*)d_in[22];
  const float* GOUTW = (const float*)d_in[23];
  const float* GOUTB = (const float*)d_in[24];
  const float* GL2G  = (const float*)d_in[25];
  const float* GL2B  = (const float*)d_in[26];
  const float* GFCW  = (const float*)d_in[27];
  const float* GFCB  = (const float*)d_in[28];
  const float* GPJW  = (const float*)d_in[29];
  const float* GPJB  = (const float*)d_in[30];
  const float* BTW   = (const float*)d_in[31];
  const float* BTB   = (const float*)d_in[32];
  const float* CLW   = (const float*)d_in[33];
  const float* CLB   = (const float*)d_in[34];

  float* ws  = (float*)d_ws;
  float* out = (float*)d_out;

  float* BUF  = ws + OFF_BUF;
  float* SSUM = ws + OFF_SSUM;
  int*   CNT  = (int*)(ws + OFF_CNT);
  unsigned* BAR = (unsigned*)(ws + OFF_BAR);
  float* Q    = ws + OFF_Q;
  float* AP   = ws + OFF_AP;
  float* QF   = ws + OFF_QF;
  float* P    = ws + OFF_P;
  float* QKV3 = ws + OFF_QKV3;
  float* XB   = ws + OFF_XB;
  float* HROW = ws + OFF_HROW;
  float* GTD  = ws + OFF_GTD;
  float* HBB  = ws + OFF_HB;
  float* KT   = ws + OFF_KT;
  float* VT   = ws + OFF_VT;
  float* AOSH = ws + OFF_AO;      // shared TN / AO / XN2 / XN3 (sequential lifetimes)
  float* GATE = ws + OFF_GATE;
  int*   EXPI = (int*)(ws + OFF_EXP);
  int*   POSI = (int*)(ws + OFF_POS);
  int*   KEEPI= (int*)(ws + OFF_KEEP);
  float* HEXP = ws + OFF_HEXP;
  float* CUR  = ws + OFF_CUR;
  float* AO2  = ws + OFF_AO2;
  bf16*  AH   = (bf16*)(ws + OFF_AH);
  bf16*  AL   = (bf16*)(ws + OFF_AL);
  bf16*  WH   = (bf16*)(ws + OFF_WH);
  bf16*  WL   = (bf16*)(ws + OFF_WL);
  float* YEXP = ws + OFF_YEXP;    // aliases AH (dead after k_l2)

  // L1: zero + cvt_a + cvt_w + tok-LN
  k_mega1<<<NZB + 4096 + 1024 + 64, 256, 0, stream>>>(
      SF, LN1G, LN1B, QKVW, TOK, LN2G, LN2B, AH, AL, WH, WL, AOSH, ws);
  // L2: K/V MFMA GEMM + Q-proj
  k_l2<<<1024 + 128, 256, 0, stream>>>(AH, AL, WH, WL, QKVB, QKVW, AOSH, KT, VT, Q);
  // L3: hd=1 attention (overwrites AOSH with AO)
  k_attn<<<dim3(512, LNUM), 256, 0, stream>>>(KT, VT, Q, AOSH);
  // L4: MoE chain
  k_mega2<<<128, 256, 0, stream>>>(AOSH, OUTW, OUTB, AP, MLPW, MLPB, QF, GPW, P,
      GSIM, GTMP, GATE, EXPI, POSI, KEEPI, SSUM, CNT, BUF,
      EW1, EB1, HEXP, EW2, EB2, YEXP, out + O_F1, out + O_F2, CUR, BAR);
  // L5: GSA chain + classifier
  k_mega3<<<64, 256, 0, stream>>>(CUR, GL1G, GL1B, AOSH, GQKVW, GQKVB, QKV3, AO2,
      GOUTW, GOUTB, XB, GL2G, GL2B, GFCW, GFCB, HROW,
      GPJW, GPJB, GTD, BTW, BTB, HBB, CLW, CLB, SSUM, CNT, out, BAR + 1);
}

// Round 8
// 961.027 us; speedup vs baseline: 1.0218x; 1.0218x over previous
//
#include <hip/hip_runtime.h>
#include <math.h>

// LRENet_2: L=4, AD=D=512, T=64, N=4096, NC=2, PROJ=256, HID=2048, CAP=16
#define LNUM 4
#define ADIM 512
#define TTOK 64
#define NSEQ 4096
#define HIDE 2048
#define CAPE 16
#define EPSV 1e-5f
#define LOG2E 1.44269504088896340736f

typedef __bf16 bf16;
typedef bf16 bf16x8 __attribute__((ext_vector_type(8)));
typedef float f32x4 __attribute__((ext_vector_type(4)));

#if __has_builtin(__builtin_amdgcn_exp2f)
#define EXP2F(x) __builtin_amdgcn_exp2f(x)
#else
#define EXP2F(x) __expf(0.69314718055994530942f * (x))
#endif

// ---------------- workspace layout (float offsets) ----------------
// zero region first (atomic-GEMM outputs + MoE buf + barrier flags)
#define OFF_BUF   0
#define OFF_SSUM  131072
#define OFF_CNT   131088
#define OFF_BAR   131104           // arrive2[128*16], arrive3[64*16], rel2, rel3
#define OFF_Q     (OFF_BAR + 3104)
#define OFF_AP    (OFF_Q    + 131072)
#define OFF_QF    (OFF_AP   + 131072)
#define OFF_P     (OFF_QF   + 131072)
#define OFF_QKV3  (OFF_P    + 65536)
#define OFF_XB    (OFF_QKV3 + 98304)
#define OFF_HROW  (OFF_XB   + 32768)
#define OFF_GTD   (OFF_HROW + 131072)
#define OFF_HB    (OFF_GTD  + 32768)
#define ZERO_N    (OFF_HB   + 16384)
#define NZB       ((ZERO_N + 255) / 256)
// non-zeroed
#define OFF_KT    ZERO_N
#define OFF_VT    (OFF_KT   + LNUM*512*NSEQ)
#define OFF_AO    (OFF_VT   + LNUM*512*NSEQ)  // shared: TN -> AO -> XN2 -> XN3
#define OFF_GATE  (OFF_AO   + 131072)
#define OFF_EXP   (OFF_GATE + 256)
#define OFF_POS   (OFF_EXP  + 256)
#define OFF_KEEP  (OFF_POS  + 256)
#define OFF_HEXP  (OFF_KEEP + 256)
#define OFF_CUR   (OFF_HEXP + LNUM*4*CAPE*HIDE)
#define OFF_AO2   (OFF_CUR  + TTOK*512)
#define OFF_AH    (OFF_AO2  + TTOK*512)   // bf16 (float slots = half count)
#define OFF_AL    (OFF_AH + LNUM*NSEQ*256)
#define OFF_WH    (OFF_AL + LNUM*NSEQ*256)
#define OFF_WL    (OFF_WH + LNUM*1024*256)
#define OFF_YEXP  OFF_AH                   // aliases AH (dead after k_l2)

// ---------------- output layout (floats) ----------------
#define O_F1   6
#define O_F2   (6 + LNUM*TTOK*512)
#define O_F2P  (O_F2 + LNUM*TTOK*512)

__device__ __forceinline__ float wave_sum(float v) {
#pragma unroll
  for (int o = 32; o > 0; o >>= 1) v += __shfl_down(v, o, 64);
  return v;
}
__device__ __forceinline__ float wave_sum_all(float v) {
#pragma unroll
  for (int o = 32; o > 0; o >>= 1) v += __shfl_xor(v, o, 64);
  return v;
}
__device__ __forceinline__ float block_sum256(float v) {
  __shared__ float r[4];
  v = wave_sum(v);
  int wid = threadIdx.x >> 6, lane = threadIdx.x & 63;
  if (lane == 0) r[wid] = v;
  __syncthreads();
  float s = r[0] + r[1] + r[2] + r[3];
  __syncthreads();
  return s;
}

// ---------------- contention-free grid barrier ----------------
// arrive[b*16]: per-block padded flag (plain stores, no RMW serialization);
// block 0 polls all flags in parallel lanes, then writes one release word
// that others read-poll (read-sharing only -> no line ping-pong).
__device__ __forceinline__ void gsync(unsigned* __restrict__ arrive, unsigned* __restrict__ release,
                                      unsigned phase, int nblk) {
  __syncthreads();
  if (blockIdx.x == 0) {
    __threadfence();
    int tid = threadIdx.x;
    if (tid >= 1 && tid < nblk) {
      while (__hip_atomic_load(&arrive[tid * 16], __ATOMIC_RELAXED, __HIP_MEMORY_SCOPE_AGENT) < phase)
        __builtin_amdgcn_s_sleep(1);
    }
    __syncthreads();
    __threadfence();
    if (tid == 0)
      __hip_atomic_store(release, phase, __ATOMIC_RELAXED, __HIP_MEMORY_SCOPE_AGENT);
  } else {
    if (threadIdx.x == 0) {
      __threadfence();
      __hip_atomic_store(&arrive[blockIdx.x * 16], phase, __ATOMIC_RELAXED, __HIP_MEMORY_SCOPE_AGENT);
      while (__hip_atomic_load(release, __ATOMIC_RELAXED, __HIP_MEMORY_SCOPE_AGENT) < phase)
        __builtin_amdgcn_s_sleep(1);
    }
    __syncthreads();
    __threadfence();
  }
}

// ---------------- LN of one 512-row by one wave ----------------
__device__ __forceinline__ void ln_row(const float* __restrict__ x,
      const float* __restrict__ G, const float* __restrict__ B, float* __restrict__ o) {
  int lane = threadIdx.x & 63;
  float4 a = *(const float4*)(x + lane * 8);
  float4 b = *(const float4*)(x + lane * 8 + 4);
  float sum = (a.x + a.y) + (a.z + a.w) + (b.x + b.y) + (b.z + b.w);
  float sq = a.x*a.x + a.y*a.y + a.z*a.z + a.w*a.w + b.x*b.x + b.y*b.y + b.z*b.z + b.w*b.w;
  sum = wave_sum_all(sum); sq = wave_sum_all(sq);
  float mu = sum * (1.f / 512.f);
  float rs = rsqrtf(sq * (1.f / 512.f) - mu * mu + EPSV);
  float4 g0 = *(const float4*)(G + lane * 8), g1 = *(const float4*)(G + lane * 8 + 4);
  float4 c0 = *(const float4*)(B + lane * 8), c1 = *(const float4*)(B + lane * 8 + 4);
  float4 o0, o1;
  o0.x = (a.x - mu) * rs * g0.x + c0.x;  o0.y = (a.y - mu) * rs * g0.y + c0.y;
  o0.z = (a.z - mu) * rs * g0.z + c0.z;  o0.w = (a.w - mu) * rs * g0.w + c0.w;
  o1.x = (b.x - mu) * rs * g1.x + c1.x;  o1.y = (b.y - mu) * rs * g1.y + c1.y;
  o1.z = (b.z - mu) * rs * g1.z + c1.z;  o1.w = (b.w - mu) * rs * g1.w + c1.w;
  *(float4*)(o + lane * 8) = o0; *(float4*)(o + lane * 8 + 4) = o1;
}

// ---------------- device GEMM tile: OUT[64 x N](n0..n0+64) (+)= IN[64 x K] @ W[N x K]^T ----------------
__device__ __forceinline__ void dev_gemm(
    const float* __restrict__ IN, const float* __restrict__ W,
    const float* __restrict__ BIAS, const float* __restrict__ RES,
    float* __restrict__ OUT, int K, int N, int n0, int kcBeg, int kcEnd,
    int doBias, int doAtomic, int act, float* sA, float* sB) {
  int tid = threadIdx.x;
  int tx = tid & 15, ty = tid >> 4;
  float acc[4][4];
  if (doBias) {
#pragma unroll
    for (int j = 0; j < 4; j++) {
      float bv = BIAS ? BIAS[n0 + tx*4 + j] : 0.f;
#pragma unroll
      for (int i = 0; i < 4; i++)
        acc[i][j] = bv + (RES ? RES[(size_t)(ty*4+i) * N + n0 + tx*4 + j] : 0.f);
    }
  } else {
#pragma unroll
    for (int i = 0; i < 4; i++)
#pragma unroll
      for (int j = 0; j < 4; j++) acc[i][j] = 0.f;
  }
  for (int kc = kcBeg; kc < kcEnd; kc += 64) {
    for (int i = tid; i < 1024; i += 256) {
      int r = i >> 4, kq = i & 15;
      float4 av = *(const float4*)(IN + (size_t)r * K + kc + kq*4);
      sA[(kq*4+0)*68 + r] = av.x; sA[(kq*4+1)*68 + r] = av.y;
      sA[(kq*4+2)*68 + r] = av.z; sA[(kq*4+3)*68 + r] = av.w;
      float4 bv = *(const float4*)(W + (size_t)(n0 + r) * K + kc + kq*4);
      sB[(kq*4+0)*68 + r] = bv.x; sB[(kq*4+1)*68 + r] = bv.y;
      sB[(kq*4+2)*68 + r] = bv.z; sB[(kq*4+3)*68 + r] = bv.w;
    }
    __syncthreads();
#pragma unroll 8
    for (int kk = 0; kk < 64; kk++) {
      float4 a4 = *(const float4*)&sA[kk*68 + ty*4];
      float4 b4 = *(const float4*)&sB[kk*68 + tx*4];
      float a[4] = {a4.x,a4.y,a4.z,a4.w}, b[4] = {b4.x,b4.y,b4.z,b4.w};
#pragma unroll
      for (int i = 0; i < 4; i++)
#pragma unroll
        for (int j = 0; j < 4; j++) acc[i][j] = fmaf(a[i], b[j], acc[i][j]);
    }
    __syncthreads();
  }
  if (doAtomic) {
#pragma unroll
    for (int i = 0; i < 4; i++)
#pragma unroll
      for (int j = 0; j < 4; j++)
        atomicAdd(&OUT[(size_t)(ty*4+i) * N + n0 + tx*4 + j], acc[i][j]);
  } else {
#pragma unroll
    for (int i = 0; i < 4; i++)
#pragma unroll
      for (int j = 0; j < 4; j++) {
        float o = acc[i][j];
        if (act == 1) o = o / (1.f + __expf(-1.702f * o));
        OUT[(size_t)(ty*4+i) * N + n0 + tx*4 + j] = o;
      }
  }
}

// transposed-W variant: W stored [K][N]
__device__ __forceinline__ void dev_gemmt(
    const float* __restrict__ IN, const float* __restrict__ W,
    float* __restrict__ OUT, int K, int N, int n0, int kcBeg, int kcEnd,
    float* sA, float* sB) {
  int tid = threadIdx.x;
  int tx = tid & 15, ty = tid >> 4;
  float acc[4][4] = {};
  for (int kc = kcBeg; kc < kcEnd; kc += 64) {
    for (int i = tid; i < 1024; i += 256) {
      int r = i >> 4, kq = i & 15;
      float4 av = *(const float4*)(IN + (size_t)r * K + kc + kq*4);
      sA[(kq*4+0)*68 + r] = av.x; sA[(kq*4+1)*68 + r] = av.y;
      sA[(kq*4+2)*68 + r] = av.z; sA[(kq*4+3)*68 + r] = av.w;
      float4 bv = *(const float4*)(W + (size_t)(kc + r) * N + n0 + kq*4);
      *(float4*)&sB[r*68 + kq*4] = bv;
    }
    __syncthreads();
#pragma unroll 8
    for (int kk = 0; kk < 64; kk++) {
      float4 a4 = *(const float4*)&sA[kk*68 + ty*4];
      float4 b4 = *(const float4*)&sB[kk*68 + tx*4];
      float a[4] = {a4.x,a4.y,a4.z,a4.w}, b[4] = {b4.x,b4.y,b4.z,b4.w};
#pragma unroll
      for (int i = 0; i < 4; i++)
#pragma unroll
        for (int j = 0; j < 4; j++) acc[i][j] = fmaf(a[i], b[j], acc[i][j]);
    }
    __syncthreads();
  }
#pragma unroll
  for (int i = 0; i < 4; i++)
#pragma unroll
    for (int j = 0; j < 4; j++)
      atomicAdd(&OUT[(size_t)(ty*4+i) * N + n0 + tx*4 + j], acc[i][j]);
}

// ================= MEGA1: zero + cvt_a + cvt_w + tok-LN =================
__global__ __launch_bounds__(256) void k_mega1(
    const float* __restrict__ SF, const float* __restrict__ LN1G, const float* __restrict__ LN1B,
    const float* __restrict__ Wqkv, const float* __restrict__ TOK,
    const float* __restrict__ LN2G, const float* __restrict__ LN2B,
    bf16* __restrict__ AH, bf16* __restrict__ AL,
    bf16* __restrict__ WH, bf16* __restrict__ WL,
    float* __restrict__ XN, float* __restrict__ ws) {
  int bid = blockIdx.x, tid = threadIdx.x;
  if (bid < NZB) {
    int i = bid * 256 + tid;
    if (i < ZERO_N) ws[i] = 0.f;
    return;
  }
  bid -= NZB;
  int wave = tid >> 6, lane = tid & 63;
  if (bid < 4096) {                    // cvt_a: LN + split-bf16, 4 rows/block
    int row = bid * 4 + wave;          // l*4096 + m
    int l = row >> 12, m = row & 4095;
    const float* src = SF + (size_t)m * (LNUM * ADIM) + l * ADIM;
    float4 a = *(const float4*)(src + lane * 8);
    float4 b = *(const float4*)(src + lane * 8 + 4);
    float sum = (a.x + a.y) + (a.z + a.w) + (b.x + b.y) + (b.z + b.w);
    float sq = a.x*a.x + a.y*a.y + a.z*a.z + a.w*a.w + b.x*b.x + b.y*b.y + b.z*b.z + b.w*b.w;
    sum = wave_sum_all(sum); sq = wave_sum_all(sq);
    float mu = sum * (1.f / 512.f);
    float rs = rsqrtf(sq * (1.f / 512.f) - mu * mu + EPSV);
    float4 g0 = *(const float4*)(LN1G + l * 512 + lane * 8);
    float4 g1 = *(const float4*)(LN1G + l * 512 + lane * 8 + 4);
    float4 c0 = *(const float4*)(LN1B + l * 512 + lane * 8);
    float4 c1 = *(const float4*)(LN1B + l * 512 + lane * 8 + 4);
    float x[8];
    x[0] = (a.x - mu) * rs * g0.x + c0.x;  x[1] = (a.y - mu) * rs * g0.y + c0.y;
    x[2] = (a.z - mu) * rs * g0.z + c0.z;  x[3] = (a.w - mu) * rs * g0.w + c0.w;
    x[4] = (b.x - mu) * rs * g1.x + c1.x;  x[5] = (b.y - mu) * rs * g1.y + c1.y;
    x[6] = (b.z - mu) * rs * g1.z + c1.z;  x[7] = (b.w - mu) * rs * g1.w + c1.w;
    bf16x8 vh, vl;
#pragma unroll
    for (int j = 0; j < 8; j++) {
      bf16 h = (bf16)x[j];
      vh[j] = h;
      vl[j] = (bf16)(x[j] - (float)h);
    }
    *(bf16x8*)(AH + (size_t)row * 512 + lane * 8) = vh;
    *(bf16x8*)(AL + (size_t)row * 512 + lane * 8) = vl;
    return;
  }
  bid -= 4096;
  if (bid < 1024) {                    // cvt_w: 4 rows/block
    int row = bid * 4 + wave;          // l*1024 + r
    int l = row >> 10, r = row & 1023;
    const float* src = Wqkv + (size_t)l * 1536 * 512 + (size_t)(512 + r) * 512 + lane * 8;
    float4 a = *(const float4*)(src);
    float4 b = *(const float4*)(src + 4);
    float x[8] = {a.x, a.y, a.z, a.w, b.x, b.y, b.z, b.w};
    bf16x8 vh, vl;
#pragma unroll
    for (int j = 0; j < 8; j++) {
      bf16 h = (bf16)x[j];
      vh[j] = h;
      vl[j] = (bf16)(x[j] - (float)h);
    }
    *(bf16x8*)(WH + (size_t)row * 512 + lane * 8) = vh;
    *(bf16x8*)(WL + (size_t)row * 512 + lane * 8) = vl;
    return;
  }
  bid -= 1024;
  {                                    // tok LN: 4 rows/block, 64 blocks
    int row = bid * 4 + wave;          // l*64 + t
    int l = row >> 6;
    ln_row(TOK + (size_t)row * 512, LN2G + l * 512, LN2B + l * 512, XN + (size_t)row * 512);
  }
}

// ================= L2: split-bf16 MFMA K/V GEMM + Q-proj GEMM =================
#define KVP 40
__global__ __launch_bounds__(256) void k_l2(
    const bf16* __restrict__ AH, const bf16* __restrict__ AL,
    const bf16* __restrict__ WH, const bf16* __restrict__ WL,
    const float* __restrict__ Bqkv, const float* __restrict__ Wqkv,
    const float* __restrict__ XN,
    float* __restrict__ KT, float* __restrict__ VT, float* __restrict__ Q) {
  __shared__ char smem[4 * 128 * KVP * sizeof(bf16)];   // 40960 B
  int bid = blockIdx.x;
  int tid = threadIdx.x;
  if (bid < 1024) {
    bf16* sAh = (bf16*)smem;
    bf16* sAl = sAh + 128 * KVP;
    bf16* sWh = sAl + 128 * KVP;
    bf16* sWl = sWh + 128 * KVP;
    int l = bid >> 8, rem = bid & 255;
    int n0 = (rem >> 5) * 128, m0 = (rem & 31) * 128;   // m fastest -> same-XCD A reuse
    int lane = tid & 63;
    int w = tid >> 6;
    int wm = w >> 1, wn = w & 1;
    const bf16* gAh = AH + ((size_t)l * 4096 + m0) * 512;
    const bf16* gAl = AL + ((size_t)l * 4096 + m0) * 512;
    const bf16* gWh = WH + ((size_t)l * 1024 + n0) * 512;
    const bf16* gWl = WL + ((size_t)l * 1024 + n0) * 512;
    int ch0 = tid * 2, ch1 = tid * 2 + 1;
    int r0 = ch0 >> 2, q0 = (ch0 & 3) * 8;
    int r1 = ch1 >> 2, q1 = (ch1 & 3) * 8;
    int fr = lane & 15, fq = (lane >> 4) * 8;
    f32x4 acc[4][4] = {};
    for (int k0 = 0; k0 < 512; k0 += 32) {
      *(bf16x8*)&sAh[r0*KVP + q0] = *(const bf16x8*)&gAh[(size_t)r0*512 + k0 + q0];
      *(bf16x8*)&sAh[r1*KVP + q1] = *(const bf16x8*)&gAh[(size_t)r1*512 + k0 + q1];
      *(bf16x8*)&sAl[r0*KVP + q0] = *(const bf16x8*)&gAl[(size_t)r0*512 + k0 + q0];
      *(bf16x8*)&sAl[r1*KVP + q1] = *(const bf16x8*)&gAl[(size_t)r1*512 + k0 + q1];
      *(bf16x8*)&sWh[r0*KVP + q0] = *(const bf16x8*)&gWh[(size_t)r0*512 + k0 + q0];
      *(bf16x8*)&sWh[r1*KVP + q1] = *(const bf16x8*)&gWh[(size_t)r1*512 + k0 + q1];
      *(bf16x8*)&sWl[r0*KVP + q0] = *(const bf16x8*)&gWl[(size_t)r0*512 + k0 + q0];
      *(bf16x8*)&sWl[r1*KVP + q1] = *(const bf16x8*)&gWl[(size_t)r1*512 + k0 + q1];
      __syncthreads();
      bf16x8 ah[4], al[4], bh[4], bl[4];
#pragma unroll
      for (int i = 0; i < 4; i++) {
        ah[i] = *(const bf16x8*)&sAh[(wm*64 + i*16 + fr)*KVP + fq];
        al[i] = *(const bf16x8*)&sAl[(wm*64 + i*16 + fr)*KVP + fq];
        bh[i] = *(const bf16x8*)&sWh[(wn*64 + i*16 + fr)*KVP + fq];
        bl[i] = *(const bf16x8*)&sWl[(wn*64 + i*16 + fr)*KVP + fq];
      }
#pragma unroll
      for (int i = 0; i < 4; i++)
#pragma unroll
        for (int j = 0; j < 4; j++) {
          acc[i][j] = __builtin_amdgcn_mfma_f32_16x16x32_bf16(ah[i], bh[j], acc[i][j], 0, 0, 0);
          acc[i][j] = __builtin_amdgcn_mfma_f32_16x16x32_bf16(ah[i], bl[j], acc[i][j], 0, 0, 0);
          acc[i][j] = __builtin_amdgcn_mfma_f32_16x16x32_bf16(al[i], bh[j], acc[i][j], 0, 0, 0);
        }
      __syncthreads();
    }
#pragma unroll
    for (int j = 0; j < 4; j++) {
      int n = n0 + wn*64 + j*16 + fr;
      float bias = Bqkv[l * 1536 + 512 + n];
      float* base = (n < 512) ? (KT + ((size_t)(l*512 + n)) * 4096)
                              : (VT + ((size_t)(l*512 + n - 512)) * 4096);
#pragma unroll
      for (int i = 0; i < 4; i++) {
        int mb = m0 + wm*64 + i*16 + (lane >> 4) * 4;
        float4 o = make_float4(acc[i][j][0] + bias, acc[i][j][1] + bias,
                               acc[i][j][2] + bias, acc[i][j][3] + bias);
        *(float4*)(base + mb) = o;
      }
    }
  } else {
    // Q-proj: 128 blocks, split-K 4 x 128, atomic into pre-zeroed Q
    float* sA = (float*)smem;
    float* sB = sA + 64 * 68;
    int rem = bid - 1024;
    int l = rem >> 5, r2 = rem & 31, kcb = r2 >> 3, nb = r2 & 7;
    dev_gemm(XN + (size_t)l * 64 * 512, Wqkv + (size_t)l * 1536 * 512,
             Bqkv + l * 1536, nullptr, Q + (size_t)l * 64 * 512,
             512, 512, nb * 64, kcb * 128, kcb * 128 + 128, kcb == 0, 1, 0, sA, sB);
  }
}

// ================= hd=1 attention (register K/V, fused min/max, native exp2) =================
__global__ __launch_bounds__(256) void k_attn(const float* __restrict__ KT, const float* __restrict__ VT,
      const float* __restrict__ Q, float* __restrict__ AO) {
  int h = blockIdx.x, l = blockIdx.y;
  int tid = threadIdx.x;
  int w = tid >> 6, lane = tid & 63;
  __shared__ float2 sacc[4][8][66];
  __shared__ float wmx[4], wmn[4];
  size_t base = ((size_t)(l * 512 + h)) * 4096 + w * 1024;
  float kv[16], vv[16];
#pragma unroll
  for (int c = 0; c < 4; c++) {
    *(float4*)&kv[c*4] = *(const float4*)(KT + base + c * 256 + lane * 4);
    *(float4*)&vv[c*4] = *(const float4*)(VT + base + c * 256 + lane * 4);
  }
  float mx = kv[0], mn = kv[0];
#pragma unroll
  for (int i = 1; i < 16; i++) { mx = fmaxf(mx, kv[i]); mn = fminf(mn, kv[i]); }
#pragma unroll
  for (int o = 32; o > 0; o >>= 1) {
    mx = fmaxf(mx, __shfl_xor(mx, o, 64));
    mn = fminf(mn, __shfl_xor(mn, o, 64));
  }
  if (lane == 0) { wmx[w] = mx; wmn[w] = mn; }
  __syncthreads();
  float km = fmaxf(fmaxf(wmx[0], wmx[1]), fmaxf(wmx[2], wmx[3]));
  float kn = fminf(fminf(wmn[0], wmn[1]), fminf(wmn[2], wmn[3]));
  float q_own = Q[((size_t)l * TTOK + lane) * 512 + h];
  float q2_own = q_own * LOG2E;
  float m2_own = ((q_own >= 0.f) ? q_own * km : q_own * kn) * LOG2E;  // exact max (hd=1)
  int rt = tid >> 5, rj = tid & 31;
  for (int cc = 0; cc < 8; cc++) {
    for (int tt = 0; tt < 8; tt++) {
      int t = cc * 8 + tt;
      float q2t = __shfl(q2_own, t, 64);
      float m2t = __shfl(m2_own, t, 64);
      float den = 0.f, num = 0.f;
#pragma unroll
      for (int i = 0; i < 16; i++) {
        float e = EXP2F(fmaf(q2t, kv[i], -m2t));
        den += e;
        num = fmaf(e, vv[i], num);
      }
      sacc[w][tt][lane] = make_float2(den, num);
    }
    __syncthreads();
    float2 a = make_float2(0.f, 0.f);
#pragma unroll
    for (int g = 0; g < 4; g++)
#pragma unroll
      for (int s2 = 0; s2 < 2; s2++) {
        float2 v = sacc[g][rt][rj + 32 * s2];
        a.x += v.x; a.y += v.y;
      }
#pragma unroll
    for (int o = 16; o > 0; o >>= 1) {
      a.x += __shfl_down(a.x, o, 32);
      a.y += __shfl_down(a.y, o, 32);
    }
    if (rj == 0) {
      int t = cc * 8 + rt;
      AO[((size_t)l * TTOK + t) * 512 + h] = a.y / a.x;
    }
    __syncthreads();
  }
}

// ================= MEGA2: out-proj -> mlp -> gate -> route/scatter -> experts -> combine =================
__global__ __launch_bounds__(256) void k_mega2(
    const float* __restrict__ AO, const float* __restrict__ OUTW, const float* __restrict__ OUTB,
    float* __restrict__ AP, const float* __restrict__ MLPW, const float* __restrict__ MLPB,
    float* __restrict__ QF, const float* __restrict__ GPW, float* __restrict__ P,
    const float* __restrict__ SIM, const float* __restrict__ TEMP,
    float* __restrict__ GATE, int* __restrict__ EXPI, int* __restrict__ POSI, int* __restrict__ KEEPI,
    float* __restrict__ SSUM, int* __restrict__ CNT, float* __restrict__ BUF,
    const float* __restrict__ EW1, const float* __restrict__ EB1, float* __restrict__ HEXP,
    const float* __restrict__ EW2, const float* __restrict__ EB2, float* __restrict__ YEXP,
    float* __restrict__ f1, float* __restrict__ f2, float* __restrict__ CUR,
    unsigned* __restrict__ arrive, unsigned* __restrict__ release) {
  __shared__ float smem[8704];
  float* sA = smem;
  float* sB = smem + 64 * 68;
  int bid = blockIdx.x;    // 128 blocks
  int tid = threadIdx.x;
  { // s1: out-proj AO @ OUTW -> AP (split-K 4)
    int l = bid >> 5, r = bid & 31, kcb = r >> 3, nb = r & 7;
    dev_gemm(AO + (size_t)l*64*512, OUTW + (size_t)l*512*512, OUTB + l*512, nullptr,
             AP + (size_t)l*64*512, 512, 512, nb*64, kcb*128, kcb*128+128, kcb == 0, 1, 0, sA, sB);
  }
  gsync(arrive, release, 1, 128);
  { // s2: mlp AP @ MLPW -> QF
    int l = bid >> 5, r = bid & 31, kcb = r >> 3, nb = r & 7;
    dev_gemm(AP + (size_t)l*64*512, MLPW + (size_t)l*512*512, MLPB + l*512, nullptr,
             QF + (size_t)l*64*512, 512, 512, nb*64, kcb*128, kcb*128+128, kcb == 0, 1, 0, sA, sB);
  }
  gsync(arrive, release, 2, 128);
  if (bid < 64) { // s3: gate proj QF @ GPW -> P
    int l = bid >> 4, r = bid & 15, kcb = r >> 2, nb = r & 3;
    dev_gemmt(QF + (size_t)l*64*512, GPW, P + (size_t)l*64*256, 512, 256,
              nb*64, kcb*128, kcb*128+128, sA, sB);
  }
  gsync(arrive, release, 3, 128);
  if (bid < 4) { // s4: gate + route + scatter, l = bid
    int l = bid;
    int t = tid >> 2, q = tid & 3;
    float* score_s = smem;               // [4][64]
    float* g_s = smem + 256;             // [64]
    int* e_s = (int*)(smem + 320);
    int* keep_s = e_s + 64;
    int* pos_s = keep_s + 64;
    const float* prow = P + ((size_t)(l * 64 + t)) * 256 + q * 64;
    float ss = 0.f, le[4] = {}, ne[4] = {};
    for (int j = 0; j < 64; j++) {
      float pv = prow[j];
      ss = fmaf(pv, pv, ss);
      float4 s4 = *(const float4*)(SIM + (size_t)(q * 64 + j) * 4);
      le[0] = fmaf(pv, s4.x, le[0]); le[1] = fmaf(pv, s4.y, le[1]);
      le[2] = fmaf(pv, s4.z, le[2]); le[3] = fmaf(pv, s4.w, le[3]);
      ne[0] = fmaf(s4.x, s4.x, ne[0]); ne[1] = fmaf(s4.y, s4.y, ne[1]);
      ne[2] = fmaf(s4.z, s4.z, ne[2]); ne[3] = fmaf(s4.w, s4.w, ne[3]);
    }
#pragma unroll
    for (int o = 2; o > 0; o >>= 1) {
      ss += __shfl_xor(ss, o, 4);
#pragma unroll
      for (int e = 0; e < 4; e++) { le[e] += __shfl_xor(le[e], o, 4); ne[e] += __shfl_xor(ne[e], o, 4); }
    }
    if (q == 0) {
      float invp = 1.f / (sqrtf(ss) + 1e-8f);
      float scale = __expf(fminf(TEMP[0], 4.6051701859880914f));  // min(temp, log 100)
      float lg[4];
#pragma unroll
      for (int e = 0; e < 4; e++) lg[e] = le[e] * invp / (sqrtf(ne[e]) + 1e-8f) * scale;
      int best = 0; float bv = lg[0];
      if (lg[1] > bv) { best = 1; bv = lg[1]; }
      if (lg[2] > bv) { best = 2; bv = lg[2]; }
      if (lg[3] > bv) { best = 3; bv = lg[3]; }
      float mxl = fmaxf(fmaxf(lg[0], lg[1]), fmaxf(lg[2], lg[3]));
      float e0 = __expf(lg[0]-mxl), e1 = __expf(lg[1]-mxl), e2 = __expf(lg[2]-mxl), e3 = __expf(lg[3]-mxl);
      float inv = 1.f / (e0 + e1 + e2 + e3);
      score_s[0*64+t] = e0*inv; score_s[1*64+t] = e1*inv;
      score_s[2*64+t] = e2*inv; score_s[3*64+t] = e3*inv;
      float sb = score_s[best*64+t];
      g_s[t] = sb; e_s[t] = best;
      GATE[l * TTOK + t] = sb;
      EXPI[l * TTOK + t] = best;
    }
    __syncthreads();
    if (tid < 64) {
      float gt = g_s[tid]; int et = e_s[tid];
      int p = 0;
      for (int u = 0; u < 64; u++)
        if (e_s[u] == et && (g_s[u] > gt || (g_s[u] == gt && u < tid))) p++;
      pos_s[tid] = p; keep_s[tid] = (p < CAPE) ? 1 : 0;
      POSI[l * TTOK + tid] = p;
      KEEPI[l * TTOK + tid] = (p < CAPE) ? 1 : 0;
    } else if (tid < 68) {
      int e = tid - 64;
      float s = 0.f; int c = 0;
      for (int u = 0; u < 64; u++) { s += score_s[e*64+u]; c += (e_s[u] == e); }
      SSUM[l * 4 + e] = s;
      CNT[l * 4 + e] = c;
    }
    __syncthreads();
    int which = tid >> 7, idx = tid & 127;
    for (int tb = 0; tb < 64; tb += 2) {
      int tt = tb + which;
      if (keep_s[tt]) {
        float4* dst = (float4*)(BUF + (((size_t)(l * 4 + e_s[tt])) * CAPE + pos_s[tt]) * 512);
        dst[idx] = ((const float4*)(QF + ((size_t)l * TTOK + tt) * 512))[idx];
      }
    }
  }
  gsync(arrive, release, 4, 128);
  { // s5: expert up-proj + gelu
    int le = bid >> 3;
    int e = le & 3;
    int col = (bid & 7) * 256 + tid;
    const float* act = BUF + (size_t)le * 16 * 512;
    const float* wp = EW1 + (size_t)e * 512 * HIDE + col;
    float acc[16];
#pragma unroll
    for (int c = 0; c < 16; c++) acc[c] = 0.f;
    for (int k0 = 0; k0 < 512; k0 += 4) {
      float4 a[16];
#pragma unroll
      for (int c = 0; c < 16; c++) a[c] = *(const float4*)(act + c * 512 + k0);
#pragma unroll
      for (int j = 0; j < 4; j++) {
        float wv = wp[(size_t)(k0 + j) * HIDE];
#pragma unroll
        for (int c = 0; c < 16; c++) acc[c] = fmaf(((const float*)&a[c])[j], wv, acc[c]);
      }
    }
    float bias = EB1[e * HIDE + col];
    float* outp = HEXP + (size_t)le * 16 * HIDE + col;
#pragma unroll
    for (int c = 0; c < 16; c++) {
      float v = acc[c] + bias;
      outp[(size_t)c * HIDE] = 0.5f * v * (1.f + erff(v * 0.70710678118654752f));
    }
  }
  gsync(arrive, release, 5, 128);
  { // s6: expert down-proj (k split over 4 waves, LDS reduce)
    int le = bid >> 3;
    int e = le & 3;
    int cl = tid & 63, kq = tid >> 6;
    int col = (bid & 7) * 64 + cl;
    const float* act = HEXP + (size_t)le * 16 * HIDE + kq * 512;
    const float* wp = EW2 + (size_t)e * HIDE * 512 + (size_t)(kq * 512) * 512 + col;
    float acc[16];
#pragma unroll
    for (int c = 0; c < 16; c++) acc[c] = 0.f;
    for (int k0 = 0; k0 < 512; k0 += 4) {
      float4 a[16];
#pragma unroll
      for (int c = 0; c < 16; c++) a[c] = *(const float4*)(act + c * HIDE + k0);
#pragma unroll
      for (int j = 0; j < 4; j++) {
        float wv = wp[(size_t)(k0 + j) * 512];
#pragma unroll
        for (int c = 0; c < 16; c++) acc[c] = fmaf(((const float*)&a[c])[j], wv, acc[c]);
      }
    }
    float* sacc = smem;   // [4][16][64]
    __syncthreads();
#pragma unroll
    for (int c = 0; c < 16; c++) sacc[(kq*16 + c)*64 + cl] = acc[c];
    __syncthreads();
    if (kq == 0) {
      float bias = EB2[e * 512 + col];
#pragma unroll
      for (int c = 0; c < 16; c++) {
        float tot = sacc[(0*16+c)*64+cl] + sacc[(1*16+c)*64+cl]
                  + sacc[(2*16+c)*64+cl] + sacc[(3*16+c)*64+cl] + bias;
        YEXP[(size_t)le * 16 * 512 + (size_t)c * 512 + col] = tot;
      }
    }
  }
  gsync(arrive, release, 6, 128);
  if (bid < 64) { // s7: combine -> f1, f2, CUR
    int t = bid;
    int d0 = tid, d1 = tid + 256;
    float a0 = 0.f, a1 = 0.f;
#pragma unroll
    for (int l = 0; l < LNUM; l++) {
      int idx = l * TTOK + t;
      if (KEEPI[idx]) {
        size_t b = (((size_t)(l * 4 + EXPI[idx])) * CAPE + POSI[idx]) * 512;
        float g = GATE[idx];
        a0 = fmaf(YEXP[b + d0], g, a0);
        a1 = fmaf(YEXP[b + d1], g, a1);
      }
      size_t r = ((size_t)l * TTOK + t) * 512;
      f1[r + d0] = a0; f1[r + d1] = a1;
      f2[r + d0] = 0.f; f2[r + d1] = 0.f;
    }
    CUR[(size_t)t * 512 + d0] = a0 * 0.25f;
    CUR[(size_t)t * 512 + d1] = a1 * 0.25f;
  }
}

// ================= MEGA3: GSA block + classifier =================
__global__ __launch_bounds__(256) void k_mega3(
    const float* __restrict__ CUR, const float* __restrict__ GL1G, const float* __restrict__ GL1B,
    float* __restrict__ XN, const float* __restrict__ GQKVW, const float* __restrict__ GQKVB,
    float* __restrict__ QKV3, float* __restrict__ AO2,
    const float* __restrict__ GOUTW, const float* __restrict__ GOUTB, float* __restrict__ XB,
    const float* __restrict__ GL2G, const float* __restrict__ GL2B,
    const float* __restrict__ GFCW, const float* __restrict__ GFCB, float* __restrict__ HROW,
    const float* __restrict__ GPJW, const float* __restrict__ GPJB, float* __restrict__ GTD,
    const float* __restrict__ BTW, const float* __restrict__ BTB, float* __restrict__ HBB,
    const float* __restrict__ CLW, const float* __restrict__ CLB,
    const float* __restrict__ SSUM, const int* __restrict__ CNT,
    float* __restrict__ out, unsigned* __restrict__ arrive, unsigned* __restrict__ release) {
  __shared__ float smem[12736];
  float* sA = smem;
  float* sB = smem + 64 * 68;
  int bid = blockIdx.x;    // 64 blocks
  int tid = threadIdx.x;
  if (tid < 64) ln_row(CUR + (size_t)bid * 512, GL1G, GL1B, XN + (size_t)bid * 512);
  gsync(arrive, release, 1, 64);
  if (bid < 48) {
    int nb = bid % 24, kcb = bid / 24;
    dev_gemm(XN, GQKVW, GQKVB, nullptr, QKV3, 512, 1536, nb*64,
             kcb*256, kcb*256+256, kcb == 0, 1, 0, sA, sB);
  }
  gsync(arrive, release, 2, 64);
  if (bid < 8) {
    int h = bid;
    float* qh = smem;                 // [64][65]
    float* kh = smem + 4160;
    float* vh = smem + 8320;
    float* ps = smem + 12480;         // [4][64]
    __syncthreads();
    for (int i = tid; i < 4096; i += 256) {
      int t = i >> 6, d = i & 63;
      qh[t*65 + d] = QKV3[(size_t)t * 1536 + h * 64 + d];
      kh[t*65 + d] = QKV3[(size_t)t * 1536 + 512 + h * 64 + d];
      vh[t*65 + d] = QKV3[(size_t)t * 1536 + 1024 + h * 64 + d];
    }
    __syncthreads();
    int w = tid >> 6, lane = tid & 63;
    for (int tt = 0; tt < 16; tt++) {
      int t = w * 16 + tt;
      float acc = 0.f;
#pragma unroll 8
      for (int d = 0; d < 64; d++) acc = fmaf(qh[t*65 + d], kh[lane*65 + d], acc);
      acc *= 0.125f;
      float m = acc;
#pragma unroll
      for (int o = 32; o > 0; o >>= 1) m = fmaxf(m, __shfl_xor(m, o, 64));
      float e = __expf(acc - m);
      float den = e;
#pragma unroll
      for (int o = 32; o > 0; o >>= 1) den += __shfl_xor(den, o, 64);
      ps[w*64 + lane] = e / den;
      __syncthreads();
      float o2 = 0.f;
#pragma unroll 8
      for (int s = 0; s < 64; s++) o2 = fmaf(ps[w*64 + s], vh[s*65 + lane], o2);
      AO2[(size_t)t * 512 + h * 64 + lane] = o2;
      __syncthreads();
    }
  }
  gsync(arrive, release, 3, 64);
  if (bid < 16) {
    int nb = bid & 7, kcb = bid >> 3;
    dev_gemm(AO2, GOUTW, GOUTB, CUR, XB, 512, 512, nb*64,
             kcb*256, kcb*256+256, kcb == 0, 1, 0, sA, sB);
  }
  gsync(arrive, release, 4, 64);
  if (tid < 64) ln_row(XB + (size_t)bid * 512, GL2G, GL2B, XN + (size_t)bid * 512);
  gsync(arrive, release, 5, 64);
  if (bid < 32)
    dev_gemm(XN, GFCW, GFCB, nullptr, HROW, 512, 2048, bid*64, 0, 512, 1, 0, 1, sA, sB);
  gsync(arrive, release, 6, 64);
  if (bid < 32) {
    int nb = bid & 7, kcb = bid >> 3;
    dev_gemm(HROW, GPJW, GPJB, XB, GTD, 2048, 512, nb*64,
             kcb*512, kcb*512+512, kcb == 0, 1, 0, sA, sB);
  }
  gsync(arrive, release, 7, 64);
  if (bid < 8) {
    int nb = bid & 3, kcb = bid >> 2;
    dev_gemm(GTD, BTW, BTB, nullptr, HBB, 512, 256, nb*64,
             kcb*256, kcb*256+256, kcb == 0, 1, 0, sA, sB);
  }
  gsync(arrive, release, 8, 64);
  if (bid == 0) {
    float p0 = 0.f, p1 = 0.f;
    for (int i = tid; i < 16384; i += 256) {
      float h = HBB[i];
      p0 = fmaf(h, CLW[i], p0);
      p1 = fmaf(h, CLW[16384 + i], p1);
    }
    p0 = block_sum256(p0);
    p1 = block_sum256(p1);
    if (tid == 0) {
      float l0 = p0 + CLB[0], l1 = p1 + CLB[1];
      out[0] = l0; out[1] = l1;
      out[2] = 1.f / (1.f + __expf(-l0));
      out[3] = 1.f / (1.f + __expf(-l1));
      out[4] = (l1 > l0) ? 1.f : 0.f;   // argmax, first max on ties
      float aux = 0.f;
      for (int i = 0; i < 16; i++) aux += (SSUM[i] * (1.f / 64.f)) * ((float)CNT[i] * (1.f / 64.f));
      out[5] = aux * 4.f * 0.01f;
    }
  }
  if (bid == 1 && tid < 8) out[O_F2P + tid] = 0.f;
}

extern "C" void kernel_launch(void* const* d_in, const int* in_sizes, int n_in,
                              void* d_out, int out_size, void* d_ws, size_t ws_size,
                              hipStream_t stream) {
  const float* SF    = (const float*)d_in[0];
  const float* TOK   = (const float*)d_in[1];
  const float* LN1G  = (const float*)d_in[2];
  const float* LN1B  = (const float*)d_in[3];
  const float* LN2G  = (const float*)d_in[4];
  const float* LN2B  = (const float*)d_in[5];
  const float* QKVW  = (const float*)d_in[6];
  const float* QKVB  = (const float*)d_in[7];
  const float* OUTW  = (const float*)d_in[8];
  const float* OUTB  = (const float*)d_in[9];
  const float* MLPW  = (const float*)d_in[10];
  const float* MLPB  = (const float*)d_in[11];
  const float* GPW   = (const float*)d_in[12];
  const float* GSIM  = (const float*)d_in[13];
  const float* GTMP  = (const float*)d_in[14];
  const float* EW1   = (const float*)d_in[15];
  const float* EB1   = (const float*)d_in[16];
  const float* EW2   = (const float*)d_in[17];
  const float* EB2   = (const float*)d_in[18];
  const float* GL1G  = (const float*)d_in[19];
  const float* GL1B  = (const float*)d_in[20];
  const float* GQKVW = (const float*)d_in[21];
  const float* GQKVB = (const float*)d_in[22];
  const float* GOUTW = (const float*)d_in[23];
  const float* GOUTB = (const float*)d_in[24];
  const float* GL2G  = (const float*)d_in[25];
  const float* GL2B  = (const float*)d_in[26];
  const float* GFCW  = (const float*)d_in[27];
  const float* GFCB  = (const float*)d_in[28];
  const float* GPJW  = (const float*)d_in[29];
  const float* GPJB  = (const float*)d_in[30];
  const float* BTW   = (const float*)d_in[31];
  const float* BTB   = (const float*)d_in[32];
  const float* CLW   = (const float*)d_in[33];
  const float* CLB   = (const float*)d_in[34];

  float* ws  = (float*)d_ws;
  float* out = (float*)d_out;

  float* BUF  = ws + OFF_BUF;
  float* SSUM = ws + OFF_SSUM;
  int*   CNT  = (int*)(ws + OFF_CNT);
  unsigned* A2 = (unsigned*)(ws + OFF_BAR);
  unsigned* A3 = (unsigned*)(ws + OFF_BAR + 2048);
  unsigned* R2 = (unsigned*)(ws + OFF_BAR + 3072);
  unsigned* R3 = (unsigned*)(ws + OFF_BAR + 3088);
  float* Q    = ws + OFF_Q;
  float* AP   = ws + OFF_AP;
  float* QF   = ws + OFF_QF;
  float* P    = ws + OFF_P;
  float* QKV3 = ws + OFF_QKV3;
  float* XB   = ws + OFF_XB;
  float* HROW = ws + OFF_HROW;
  float* GTD  = ws + OFF_GTD;
  float* HBB  = ws + OFF_HB;
  float* KT   = ws + OFF_KT;
  float* VT   = ws + OFF_VT;
  float* AOSH = ws + OFF_AO;      // shared TN / AO / XN2 / XN3 (sequential lifetimes)
  float* GATE = ws + OFF_GATE;
  int*   EXPI = (int*)(ws + OFF_EXP);
  int*   POSI = (int*)(ws + OFF_POS);
  int*   KEEPI= (int*)(ws + OFF_KEEP);
  float* HEXP = ws + OFF_HEXP;
  float* CUR  = ws + OFF_CUR;
  float* AO2  = ws + OFF_AO2;
  bf16*  AH   = (bf16*)(ws + OFF_AH);
  bf16*  AL   = (bf16*)(ws + OFF_AL);
  bf16*  WH   = (bf16*)(ws + OFF_WH);
  bf16*  WL   = (bf16*)(ws + OFF_WL);
  float* YEXP = ws + OFF_YEXP;    // aliases AH (dead after k_l2)

  // L1: zero + cvt_a + cvt_w + tok-LN
  k_mega1<<<NZB + 4096 + 1024 + 64, 256, 0, stream>>>(
      SF, LN1G, LN1B, QKVW, TOK, LN2G, LN2B, AH, AL, WH, WL, AOSH, ws);
  // L2: K/V MFMA GEMM + Q-proj
  k_l2<<<1024 + 128, 256, 0, stream>>>(AH, AL, WH, WL, QKVB, QKVW, AOSH, KT, VT, Q);
  // L3: hd=1 attention (overwrites AOSH with AO)
  k_attn<<<dim3(512, LNUM), 256, 0, stream>>>(KT, VT, Q, AOSH);
  // L4: MoE chain
  k_mega2<<<128, 256, 0, stream>>>(AOSH, OUTW, OUTB, AP, MLPW, MLPB, QF, GPW, P,
      GSIM, GTMP, GATE, EXPI, POSI, KEEPI, SSUM, CNT, BUF,
      EW1, EB1, HEXP, EW2, EB2, YEXP, out + O_F1, out + O_F2, CUR, A2, R2);
  // L5: GSA chain + classifier
  k_mega3<<<64, 256, 0, stream>>>(CUR, GL1G, GL1B, AOSH, GQKVW, GQKVB, QKV3, AO2,
      GOUTW, GOUTB, XB, GL2G, GL2B, GFCW, GFCB, HROW,
      GPJW, GPJB, GTD, BTW, BTB, HBB, CLW, CLB, SSUM, CNT, out, A3, R3);
}